// Round 10
// baseline (194.807 us; speedup 1.0000x reference)
//
#include <hip/hip_runtime.h>

typedef unsigned short ushort_t;
typedef __bf16 bf16x8 __attribute__((ext_vector_type(8)));
typedef unsigned short ushortx8 __attribute__((ext_vector_type(8)));
typedef unsigned short ushortx4 __attribute__((ext_vector_type(4)));
typedef unsigned int uintx4 __attribute__((ext_vector_type(4)));
typedef float floatx4 __attribute__((ext_vector_type(4)));

__device__ inline void load16_lds(const ushort_t* g, ushort_t* l) {
  __builtin_amdgcn_global_load_lds(
      (__attribute__((address_space(1))) void*)(g),
      (__attribute__((address_space(3))) void*)(l),
      16, 0, 0);
}

__device__ inline float bf2f(ushort_t u) {
  unsigned int v = ((unsigned int)u) << 16;
  return __builtin_bit_cast(float, v);
}

__device__ inline ushort_t f2bf(float f) {
  unsigned int u = __builtin_bit_cast(unsigned int, f);
  u += 0x7fffu + ((u >> 16) & 1u);
  return (ushort_t)(u >> 16);
}

__device__ inline bf16x8 ldfrag(const ushort_t* p) {
  return __builtin_bit_cast(bf16x8, *(const ushortx8*)p);
}

// per-wave dtype sniff; P(wrong | fp32) ~= 0.55^64 ~= 4e-17.
__device__ inline bool sniff_f32(const ushort_t* x, int lane_off) {
  float v = fabsf(bf2f(x[lane_off]));
  bool big = !(v < 1e4f);
  return __ballot(big) != 0ull;
}

// ---------------------------------------------------------------------------
// Canonicalize inputs to bf16 (x, Wq, Wk, Wv) and fp32 biases; inline sniff.
// ---------------------------------------------------------------------------
__global__ __launch_bounds__(256) void convert_all(
    const void* __restrict__ x,
    const void* __restrict__ wq, const void* __restrict__ wk, const void* __restrict__ wv,
    const void* __restrict__ bq, const void* __restrict__ bk, const void* __restrict__ bv,
    ushort_t* __restrict__ xb, ushort_t* __restrict__ wqb,
    ushort_t* __restrict__ wkb, ushort_t* __restrict__ wvb,
    float* __restrict__ biasf, int* __restrict__ flag)
{
  const bool f32 = sniff_f32((const ushort_t*)x, (int)(threadIdx.x & 63));
  const int seg = blockIdx.y;
  if (seg == 4) {
    if (blockIdx.x == 0 && threadIdx.x == 0) *flag = f32 ? 1 : 0;
    const int i = blockIdx.x * 256 + threadIdx.x;
    if (i >= 1024) return;
    const void* bs[3] = {bq, bk, bv};
#pragma unroll
    for (int k = 0; k < 3; ++k)
      biasf[k * 1024 + i] = f32 ? ((const float*)bs[k])[i] : bf2f(((const ushort_t*)bs[k])[i]);
    return;
  }
  const void* src = (seg == 0) ? x : (seg == 1) ? wq : (seg == 2) ? wk : wv;
  ushort_t* dst   = (seg == 0) ? xb : (seg == 1) ? wqb : (seg == 2) ? wkb : wvb;
  const int n = (seg == 0) ? 4194304 : 1048576;
  const int i = (blockIdx.x * 256 + threadIdx.x) * 8;
  if (i >= n) return;
  if (f32) {
    const float* s = (const float*)src + i;
    ushortx8 o;
#pragma unroll
    for (int j = 0; j < 8; ++j) o[j] = f2bf(s[j]);
    *(ushortx8*)(dst + i) = o;
  } else {
    *(ushortx8*)(dst + i) = *(const ushortx8*)((const ushort_t*)src + i);
  }
}

// ---------------------------------------------------------------------------
// QKV projection: out = x @ W^T + b; Q scaled by log2(e)/sqrt(64).
// which==2 (V) writes DIRECTLY in transposed layout Vt(bh,hs,s).
// ---------------------------------------------------------------------------
__global__ __launch_bounds__(256, 2) void qkv_gemm(
    const ushort_t* __restrict__ x,
    const ushort_t* __restrict__ Wq, const ushort_t* __restrict__ Wk,
    const ushort_t* __restrict__ Wv, const float* __restrict__ biasf,
    ushort_t* __restrict__ Qo, ushort_t* __restrict__ Ko, ushort_t* __restrict__ Vt)
{
  __shared__ __attribute__((aligned(16))) ushort_t As[128 * 32];
  __shared__ __attribute__((aligned(16))) ushort_t Bs[128 * 32];

  const int which = blockIdx.z;
  const ushort_t* W = (which == 0) ? Wq : (which == 1) ? Wk : Wv;
  const float oscale = (which == 0) ? 0.18033688011112042f : 1.0f;

  const int n0 = blockIdx.x * 128;
  const int m0 = blockIdx.y * 128;

  const int tid  = threadIdx.x;
  const int wave = tid >> 6;
  const int lane = tid & 63;
  const int ln   = lane & 15;
  const int quad = lane >> 4;
  const int wm = (wave >> 1) * 64;
  const int wn = (wave & 1) * 64;

  floatx4 acc[4][4];
#pragma unroll
  for (int i = 0; i < 4; ++i)
#pragma unroll
    for (int j = 0; j < 4; ++j) acc[i][j] = floatx4{0.f, 0.f, 0.f, 0.f};

  const int c1 = tid, c2 = tid + 256;
  const ushort_t* ga1 = x + (m0 + (c1 >> 2)) * 1024 + (c1 & 3) * 8;
  const ushort_t* ga2 = x + (m0 + (c2 >> 2)) * 1024 + (c2 & 3) * 8;
  const ushort_t* gb1 = W + (n0 + (c1 >> 2)) * 1024 + (c1 & 3) * 8;
  const ushort_t* gb2 = W + (n0 + (c2 >> 2)) * 1024 + (c2 & 3) * 8;
  ushort_t* la1 = As + wave * 512;
  ushort_t* la2 = As + 2048 + wave * 512;
  ushort_t* lb1 = Bs + wave * 512;
  ushort_t* lb2 = Bs + 2048 + wave * 512;

  for (int kt = 0; kt < 1024; kt += 32) {
    __syncthreads();
    load16_lds(ga1 + kt, la1);
    load16_lds(ga2 + kt, la2);
    load16_lds(gb1 + kt, lb1);
    load16_lds(gb2 + kt, lb2);
    __syncthreads();

    bf16x8 af[4], bfr[4];
#pragma unroll
    for (int mi = 0; mi < 4; ++mi)
      af[mi] = ldfrag(As + (wm + mi * 16 + ln) * 32 + quad * 8);
#pragma unroll
    for (int ni = 0; ni < 4; ++ni)
      bfr[ni] = ldfrag(Bs + (wn + ni * 16 + ln) * 32 + quad * 8);
#pragma unroll
    for (int mi = 0; mi < 4; ++mi)
#pragma unroll
      for (int ni = 0; ni < 4; ++ni)
        acc[mi][ni] = __builtin_amdgcn_mfma_f32_16x16x32_bf16(af[mi], bfr[ni], acc[mi][ni], 0, 0, 0);
  }

  float bvv[4];
#pragma unroll
  for (int ni = 0; ni < 4; ++ni) bvv[ni] = biasf[which * 1024 + n0 + wn + ni * 16 + ln];

  if (which == 2) {
#pragma unroll
    for (int mi = 0; mi < 4; ++mi)
#pragma unroll
      for (int ni = 0; ni < 4; ++ni) {
        const int col = n0 + wn + ni * 16 + ln;
        const int row0 = m0 + wm + mi * 16 + quad * 4;
        const int b = row0 >> 11, s0 = row0 & 2047;
        const int h = col >> 6, hs = col & 63;
        ushortx4 pk;
#pragma unroll
        for (int r = 0; r < 4; ++r) pk[r] = f2bf(acc[mi][ni][r] + bvv[ni]);
        *(ushortx4*)(Vt + ((size_t)((b * 16 + h) * 64 + hs)) * 2048 + s0) = pk;
      }
  } else {
    ushort_t* out = (which == 0) ? Qo : Ko;
#pragma unroll
    for (int mi = 0; mi < 4; ++mi)
#pragma unroll
      for (int ni = 0; ni < 4; ++ni) {
        const int col = n0 + wn + ni * 16 + ln;
#pragma unroll
        for (int r = 0; r < 4; ++r) {
          const int row = m0 + wm + mi * 16 + quad * 4 + r;
          out[row * 1024 + col] = f2bf((acc[mi][ni][r] + bvv[ni]) * oscale);
        }
      }
  }
}

// ---------------------------------------------------------------------------
// Flash attention v9 — LDS-shared K/V tiles (vmem bytes halved), causal.
// Block = 128 thr (2 waves) covering 128 q-rows: wave w owns rows +64w
// (flash8's proven q=64/wave body). Each kv-tile (K 8KB + V^T 8KB) is
// global-loaded ONCE per block: each wave loads half into VGPRs, ds_writes
// it, one barrier, both waves ds_read full A-frags from padded LDS (144B
// rows -> ~2-way conflicts, free). Double-buffered LDS, 1 barrier/tile;
// t+1 global loads issue AFTER the barrier so the drain never blocks them.
// Per-wave epilogues are independent (distinct q rows) — no combine.
// vmem: 16896 -> 8704 tile-loads = 139 MB (floor ~22.6 us at ~11 B/cyc/CU).
// ---------------------------------------------------------------------------
__global__ __launch_bounds__(128) void flash9(
    const ushort_t* __restrict__ Q, const ushort_t* __restrict__ Kx,
    const ushort_t* __restrict__ Vt, void* __restrict__ out,
    const int* __restrict__ flag)
{
  __shared__ __attribute__((aligned(16))) ushort_t sK[2][64 * 72];  // 144B rows
  __shared__ __attribute__((aligned(16))) ushort_t sV[2][64 * 72];

  const bool f32o = (*flag != 0);
  const int tid  = threadIdx.x;
  const int wave = tid >> 6;
  const int lane = tid & 63;
  const int ln = lane & 15, quad = lane >> 4;

  // bpermute constants for the C->A quad permutation
  const int idxA = (ln + 32 * (quad & 1)) * 4;
  const int idxB = idxA + 64;
  const bool hiq = (quad >> 1) != 0;

  // staging lane map: 32 rows x 128B per wave-half
  const int rl   = (lane & 15) + 16 * ((lane >> 5) & 1);  // row 0..31
  const int hsel = (lane >> 4) & 1;                        // 64B half

  // grid 512: i<256 big chunks (c=15-s), i>=256 complementary smalls (c=s);
  // CU k tends to get blocks k and k+256 -> per-CU work ~constant.
  const int i = blockIdx.x;
  const int s = (i < 256) ? (i >> 5) : ((i - 256) >> 5);
  const int c = (i < 256) ? (15 - s) : s;                  // 128-row chunk 0..15
  const int bhi = i & 31;
  const int bh = (bhi & 7) * 4 + (bhi >> 3);               // XCD swizzle
  const int b = bh >> 4, h = bh & 15;
  const int qw = c * 128 + wave * 64;
  const int ntiles = 2 * c + 2;
  const int mytiles = 2 * c + wave;   // wave computes tile t iff t <= mytiles

  const ushort_t* kbase = Kx + ((size_t)b * 2048) * 1024 + h * 64;
  const ushort_t* vbase = Vt + (size_t)bh * 64 * 2048;

  bf16x8 qf[4][2];
#pragma unroll
  for (int bi = 0; bi < 4; ++bi)
#pragma unroll
    for (int ks = 0; ks < 2; ++ks)
      qf[bi][ks] = ldfrag(Q + (size_t)(b * 2048 + qw + bi * 16 + ln) * 1024 + h * 64 + ks * 32 + quad * 8);

  floatx4 ot[4][4];
#pragma unroll
  for (int ai = 0; ai < 4; ++ai)
#pragma unroll
    for (int bi = 0; bi < 4; ++bi) ot[ai][bi] = floatx4{0.f, 0.f, 0.f, 0.f};
  float li[4] = {0.f, 0.f, 0.f, 0.f};

  // prologue: stage tile 0 (this wave's half) into VGPRs
  uintx4 stgK[4], stgV[4];
  {
    const ushort_t* kg = kbase + (size_t)(0 + 32 * wave + rl) * 1024 + hsel * 32;
    const ushort_t* vg = vbase + (size_t)(32 * wave + rl) * 2048 + 0 + hsel * 32;
#pragma unroll
    for (int c16 = 0; c16 < 4; ++c16) {
      stgK[c16] = *(const uintx4*)(kg + c16 * 8);
      stgV[c16] = *(const uintx4*)(vg + c16 * 8);
    }
  }

  for (int t = 0; t < ntiles; ++t) {
    const int kv0 = t * 64;
    const int buf = t & 1;

    // A: commit staged half-tile to LDS
    {
      ushort_t* wk = sK[buf] + (32 * wave + rl) * 72 + hsel * 32;
      ushort_t* wv = sV[buf] + (32 * wave + rl) * 72 + hsel * 32;
#pragma unroll
      for (int c16 = 0; c16 < 4; ++c16) {
        *(uintx4*)(wk + c16 * 8) = stgK[c16];
        *(uintx4*)(wv + c16 * 8) = stgV[c16];
      }
    }
    __syncthreads();  // B: tile visible to both waves (dbuf -> 1 barrier/tile)

    // C: issue next tile's global loads (in flight across all of D/E)
    if (t + 1 < ntiles) {
      const int kvn = (t + 1) * 64;
      const ushort_t* kg = kbase + (size_t)(kvn + 32 * wave + rl) * 1024 + hsel * 32;
      const ushort_t* vg = vbase + (size_t)(32 * wave + rl) * 2048 + kvn + hsel * 32;
#pragma unroll
      for (int c16 = 0; c16 < 4; ++c16) {
        stgK[c16] = *(const uintx4*)(kg + c16 * 8);
        stgV[c16] = *(const uintx4*)(vg + c16 * 8);
      }
    }

    // D/E: compute (wave-uniform skip for wave 0's unused last tile)
    if (t <= mytiles) {
      const bool diag = (t == mytiles);

      bf16x8 kf[4][2], vf[4][2];
#pragma unroll
      for (int mi = 0; mi < 4; ++mi)
#pragma unroll
        for (int ks = 0; ks < 2; ++ks) {
          kf[mi][ks] = ldfrag(sK[buf] + (mi * 16 + ln) * 72 + ks * 32 + quad * 8);
          vf[mi][ks] = ldfrag(sV[buf] + (mi * 16 + ln) * 72 + ks * 32 + quad * 8);
        }

#pragma unroll
      for (int bi = 0; bi < 4; ++bi) {
        floatx4 st[4];
#pragma unroll
        for (int mi = 0; mi < 4; ++mi) st[mi] = floatx4{0.f, 0.f, 0.f, 0.f};
#pragma unroll
        for (int mi = 0; mi < 4; ++mi) {
          st[mi] = __builtin_amdgcn_mfma_f32_16x16x32_bf16(kf[mi][0], qf[bi][0], st[mi], 0, 0, 0);
          st[mi] = __builtin_amdgcn_mfma_f32_16x16x32_bf16(kf[mi][1], qf[bi][1], st[mi], 0, 0, 0);
        }

        const int qrow = qw + bi * 16 + ln;
        float p[4][4];
        if (diag) {
#pragma unroll
          for (int mi = 0; mi < 4; ++mi)
#pragma unroll
            for (int r = 0; r < 4; ++r) {
              const int kv = kv0 + mi * 16 + quad * 4 + r;
              const float e = __builtin_amdgcn_exp2f(st[mi][r]);
              p[mi][r] = (kv > qrow) ? 0.f : e;
            }
        } else {
#pragma unroll
          for (int mi = 0; mi < 4; ++mi)
#pragma unroll
            for (int r = 0; r < 4; ++r) p[mi][r] = __builtin_amdgcn_exp2f(st[mi][r]);
        }

        unsigned d[4][2];
#pragma unroll
        for (int mi = 0; mi < 4; ++mi) {
          li[bi] += (p[mi][0] + p[mi][1]) + (p[mi][2] + p[mi][3]);
          d[mi][0] = __builtin_amdgcn_perm(
              __builtin_bit_cast(unsigned, p[mi][1]), __builtin_bit_cast(unsigned, p[mi][0]), 0x07060302u);
          d[mi][1] = __builtin_amdgcn_perm(
              __builtin_bit_cast(unsigned, p[mi][3]), __builtin_bit_cast(unsigned, p[mi][2]), 0x07060302u);
        }

        bf16x8 pb[2];
#pragma unroll
        for (int ks = 0; ks < 2; ++ks) {
          uintx4 w;
#pragma unroll
          for (int jj = 0; jj < 4; ++jj) {
            const int idx = (jj >> 1) ? idxB : idxA;
            const int lo = __builtin_amdgcn_ds_bpermute(idx, (int)d[2 * ks][jj & 1]);
            const int hi = __builtin_amdgcn_ds_bpermute(idx, (int)d[2 * ks + 1][jj & 1]);
            w[jj] = (unsigned)(hiq ? hi : lo);
          }
          pb[ks] = __builtin_bit_cast(bf16x8, w);
        }

#pragma unroll
        for (int ai = 0; ai < 4; ++ai) {
          ot[ai][bi] = __builtin_amdgcn_mfma_f32_16x16x32_bf16(vf[ai][0], pb[0], ot[ai][bi], 0, 0, 0);
          ot[ai][bi] = __builtin_amdgcn_mfma_f32_16x16x32_bf16(vf[ai][1], pb[1], ot[ai][bi], 0, 0, 0);
        }
      }
    }
  }

  // per-wave epilogue (independent q rows; no cross-wave combine)
#pragma unroll
  for (int bi = 0; bi < 4; ++bi) {
    li[bi] += __shfl_xor(li[bi], 16);
    li[bi] += __shfl_xor(li[bi], 32);
    const float inv = 1.0f / li[bi];
    const int qrow = qw + bi * 16 + ln;
    if (f32o) {
      float* of = (float*)out;
#pragma unroll
      for (int ai = 0; ai < 4; ++ai) {
        floatx4 o;
#pragma unroll
        for (int r = 0; r < 4; ++r) o[r] = ot[ai][bi][r] * inv;
        *(floatx4*)(of + (size_t)(b * 2048 + qrow) * 1024 + h * 64 + ai * 16 + quad * 4) = o;
      }
    } else {
      ushort_t* ob = (ushort_t*)out;
#pragma unroll
      for (int ai = 0; ai < 4; ++ai) {
        ushortx4 pk;
#pragma unroll
        for (int r = 0; r < 4; ++r) pk[r] = f2bf(ot[ai][bi][r] * inv);
        *(ushortx4*)(ob + (size_t)(b * 2048 + qrow) * 1024 + h * 64 + ai * 16 + quad * 4) = pk;
      }
    }
  }
}

// ---------------------------------------------------------------------------
extern "C" void kernel_launch(void* const* d_in, const int* in_sizes, int n_in,
                              void* d_out, int out_size, void* d_ws, size_t ws_size,
                              hipStream_t stream) {
  char* w = (char*)d_ws;
  int* flag = (int*)w;
  size_t off = 256;
  ushort_t* xb  = (ushort_t*)(w + off); off += (size_t)4194304 * 2;
  ushort_t* wqb = (ushort_t*)(w + off); off += (size_t)1048576 * 2;
  ushort_t* wkb = (ushort_t*)(w + off); off += (size_t)1048576 * 2;
  ushort_t* wvb = (ushort_t*)(w + off); off += (size_t)1048576 * 2;
  float* biasf  = (float*)(w + off);    off += (size_t)3 * 1024 * 4;
  ushort_t* Qw  = (ushort_t*)(w + off); off += (size_t)4194304 * 2;
  ushort_t* Kw  = (ushort_t*)(w + off); off += (size_t)4194304 * 2;
  ushort_t* Vtw = (ushort_t*)(w + off);

  convert_all<<<dim3(2048, 5), 256, 0, stream>>>(
      d_in[0], d_in[1], d_in[3], d_in[5], d_in[2], d_in[4], d_in[6],
      xb, wqb, wkb, wvb, biasf, flag);
  qkv_gemm<<<dim3(8, 32, 3), 256, 0, stream>>>(xb, wqb, wkb, wvb, biasf, Qw, Kw, Vtw);
  flash9<<<512, 128, 0, stream>>>(Qw, Kw, Vtw, d_out, flag);
}

// Round 11
// 171.144 us; speedup vs baseline: 1.1383x; 1.1383x over previous
//
#include <hip/hip_runtime.h>

typedef unsigned short ushort_t;
typedef __bf16 bf16x8 __attribute__((ext_vector_type(8)));
typedef unsigned short ushortx8 __attribute__((ext_vector_type(8)));
typedef unsigned short ushortx4 __attribute__((ext_vector_type(4)));
typedef unsigned int uintx4 __attribute__((ext_vector_type(4)));
typedef float floatx4 __attribute__((ext_vector_type(4)));

__device__ inline void load16_lds(const ushort_t* g, ushort_t* l) {
  __builtin_amdgcn_global_load_lds(
      (__attribute__((address_space(1))) void*)(g),
      (__attribute__((address_space(3))) void*)(l),
      16, 0, 0);
}

__device__ inline float bf2f(ushort_t u) {
  unsigned int v = ((unsigned int)u) << 16;
  return __builtin_bit_cast(float, v);
}

__device__ inline ushort_t f2bf(float f) {
  unsigned int u = __builtin_bit_cast(unsigned int, f);
  u += 0x7fffu + ((u >> 16) & 1u);
  return (ushort_t)(u >> 16);
}

__device__ inline bf16x8 ldfrag(const ushort_t* p) {
  return __builtin_bit_cast(bf16x8, *(const ushortx8*)p);
}

// per-wave dtype sniff; P(wrong | fp32) ~= 0.55^64 ~= 4e-17.
__device__ inline bool sniff_f32(const ushort_t* x, int lane_off) {
  float v = fabsf(bf2f(x[lane_off]));
  bool big = !(v < 1e4f);
  return __ballot(big) != 0ull;
}

// ---------------------------------------------------------------------------
// Canonicalize inputs to bf16 (x, Wq, Wk, Wv) and fp32 biases; inline sniff.
// ---------------------------------------------------------------------------
__global__ __launch_bounds__(256) void convert_all(
    const void* __restrict__ x,
    const void* __restrict__ wq, const void* __restrict__ wk, const void* __restrict__ wv,
    const void* __restrict__ bq, const void* __restrict__ bk, const void* __restrict__ bv,
    ushort_t* __restrict__ xb, ushort_t* __restrict__ wqb,
    ushort_t* __restrict__ wkb, ushort_t* __restrict__ wvb,
    float* __restrict__ biasf, int* __restrict__ flag)
{
  const bool f32 = sniff_f32((const ushort_t*)x, (int)(threadIdx.x & 63));
  const int seg = blockIdx.y;
  if (seg == 4) {
    if (blockIdx.x == 0 && threadIdx.x == 0) *flag = f32 ? 1 : 0;
    const int i = blockIdx.x * 256 + threadIdx.x;
    if (i >= 1024) return;
    const void* bs[3] = {bq, bk, bv};
#pragma unroll
    for (int k = 0; k < 3; ++k)
      biasf[k * 1024 + i] = f32 ? ((const float*)bs[k])[i] : bf2f(((const ushort_t*)bs[k])[i]);
    return;
  }
  const void* src = (seg == 0) ? x : (seg == 1) ? wq : (seg == 2) ? wk : wv;
  ushort_t* dst   = (seg == 0) ? xb : (seg == 1) ? wqb : (seg == 2) ? wkb : wvb;
  const int n = (seg == 0) ? 4194304 : 1048576;
  const int i = (blockIdx.x * 256 + threadIdx.x) * 8;
  if (i >= n) return;
  if (f32) {
    const float* s = (const float*)src + i;
    ushortx8 o;
#pragma unroll
    for (int j = 0; j < 8; ++j) o[j] = f2bf(s[j]);
    *(ushortx8*)(dst + i) = o;
  } else {
    *(ushortx8*)(dst + i) = *(const ushortx8*)((const ushort_t*)src + i);
  }
}

// ---------------------------------------------------------------------------
// QKV projection: out = x @ W^T + b; Q scaled by log2(e)/sqrt(64).
// which==2 (V) writes DIRECTLY in transposed layout Vt(bh,hs,s).
// ---------------------------------------------------------------------------
__global__ __launch_bounds__(256, 2) void qkv_gemm(
    const ushort_t* __restrict__ x,
    const ushort_t* __restrict__ Wq, const ushort_t* __restrict__ Wk,
    const ushort_t* __restrict__ Wv, const float* __restrict__ biasf,
    ushort_t* __restrict__ Qo, ushort_t* __restrict__ Ko, ushort_t* __restrict__ Vt)
{
  __shared__ __attribute__((aligned(16))) ushort_t As[128 * 32];
  __shared__ __attribute__((aligned(16))) ushort_t Bs[128 * 32];

  const int which = blockIdx.z;
  const ushort_t* W = (which == 0) ? Wq : (which == 1) ? Wk : Wv;
  const float oscale = (which == 0) ? 0.18033688011112042f : 1.0f;

  const int n0 = blockIdx.x * 128;
  const int m0 = blockIdx.y * 128;

  const int tid  = threadIdx.x;
  const int wave = tid >> 6;
  const int lane = tid & 63;
  const int ln   = lane & 15;
  const int quad = lane >> 4;
  const int wm = (wave >> 1) * 64;
  const int wn = (wave & 1) * 64;

  floatx4 acc[4][4];
#pragma unroll
  for (int i = 0; i < 4; ++i)
#pragma unroll
    for (int j = 0; j < 4; ++j) acc[i][j] = floatx4{0.f, 0.f, 0.f, 0.f};

  const int c1 = tid, c2 = tid + 256;
  const ushort_t* ga1 = x + (m0 + (c1 >> 2)) * 1024 + (c1 & 3) * 8;
  const ushort_t* ga2 = x + (m0 + (c2 >> 2)) * 1024 + (c2 & 3) * 8;
  const ushort_t* gb1 = W + (n0 + (c1 >> 2)) * 1024 + (c1 & 3) * 8;
  const ushort_t* gb2 = W + (n0 + (c2 >> 2)) * 1024 + (c2 & 3) * 8;
  ushort_t* la1 = As + wave * 512;
  ushort_t* la2 = As + 2048 + wave * 512;
  ushort_t* lb1 = Bs + wave * 512;
  ushort_t* lb2 = Bs + 2048 + wave * 512;

  for (int kt = 0; kt < 1024; kt += 32) {
    __syncthreads();
    load16_lds(ga1 + kt, la1);
    load16_lds(ga2 + kt, la2);
    load16_lds(gb1 + kt, lb1);
    load16_lds(gb2 + kt, lb2);
    __syncthreads();

    bf16x8 af[4], bfr[4];
#pragma unroll
    for (int mi = 0; mi < 4; ++mi)
      af[mi] = ldfrag(As + (wm + mi * 16 + ln) * 32 + quad * 8);
#pragma unroll
    for (int ni = 0; ni < 4; ++ni)
      bfr[ni] = ldfrag(Bs + (wn + ni * 16 + ln) * 32 + quad * 8);
#pragma unroll
    for (int mi = 0; mi < 4; ++mi)
#pragma unroll
      for (int ni = 0; ni < 4; ++ni)
        acc[mi][ni] = __builtin_amdgcn_mfma_f32_16x16x32_bf16(af[mi], bfr[ni], acc[mi][ni], 0, 0, 0);
  }

  float bvv[4];
#pragma unroll
  for (int ni = 0; ni < 4; ++ni) bvv[ni] = biasf[which * 1024 + n0 + wn + ni * 16 + ln];

  if (which == 2) {
#pragma unroll
    for (int mi = 0; mi < 4; ++mi)
#pragma unroll
      for (int ni = 0; ni < 4; ++ni) {
        const int col = n0 + wn + ni * 16 + ln;
        const int row0 = m0 + wm + mi * 16 + quad * 4;
        const int b = row0 >> 11, s0 = row0 & 2047;
        const int h = col >> 6, hs = col & 63;
        ushortx4 pk;
#pragma unroll
        for (int r = 0; r < 4; ++r) pk[r] = f2bf(acc[mi][ni][r] + bvv[ni]);
        *(ushortx4*)(Vt + ((size_t)((b * 16 + h) * 64 + hs)) * 2048 + s0) = pk;
      }
  } else {
    ushort_t* out = (which == 0) ? Qo : Ko;
#pragma unroll
    for (int mi = 0; mi < 4; ++mi)
#pragma unroll
      for (int ni = 0; ni < 4; ++ni) {
        const int col = n0 + wn + ni * 16 + ln;
#pragma unroll
        for (int r = 0; r < 4; ++r) {
          const int row = m0 + wm + mi * 16 + quad * 4 + r;
          out[row * 1024 + col] = f2bf((acc[mi][ni][r] + bvv[ni]) * oscale);
        }
      }
  }
}

// ---------------------------------------------------------------------------
// Flash attention v10 — flash8's q=64/wave body + constant-makespan blocks.
// Block = 256 thr (4 waves), owns the 64-row q-chunk PAIR (31-pr, pr) in two
// phases. Per phase: all 4 waves cover the SAME 64 q-rows, kv-tiles split
// t ≡ wave (mod 4); additive no-max combine (2-round LDS tree). Per-wave
// work = (c+1)/4 + (32-c)/4 ≈ 8.25 tiles in EVERY block -> all 512 blocks
// resident (2/CU), 8 waves/CU live the whole kernel, no drain tail.
// Loop body identical to flash8 (global->VGPR K/V, bpermute P-transform,
// no barrier/fence in the tile loop).
// ---------------------------------------------------------------------------
__global__ __launch_bounds__(256) void flash10(
    const ushort_t* __restrict__ Q, const ushort_t* __restrict__ Kx,
    const ushort_t* __restrict__ Vt, void* __restrict__ out,
    const int* __restrict__ flag)
{
  __shared__ __attribute__((aligned(16))) float CbA[64][68];
  __shared__ __attribute__((aligned(16))) float CbB[64][68];
  __shared__ float lbA[64][4], lbB[64][4];

  const bool f32o = (*flag != 0);
  const int tid  = threadIdx.x;
  const int wave = tid >> 6;
  const int lane = tid & 63;
  const int ln = lane & 15, quad = lane >> 4;

  // bpermute constants for the C->A quad permutation
  const int idxA = (ln + 32 * (quad & 1)) * 4;
  const int idxB = idxA + 64;
  const bool hiq = (quad >> 1) != 0;

  // grid 512 = 8 xcd x (4 bh x 16 pairs)
  const int i = blockIdx.x;
  const int xcd = i & 7, j = i >> 3;
  const int bh = xcd * 4 + (j & 3);
  const int pr = j >> 2;                 // 0..15
  const int b = bh >> 4, h = bh & 15;

  const ushort_t* kbase = Kx + ((size_t)b * 2048) * 1024 + h * 64;
  const ushort_t* vbase = Vt + (size_t)bh * 64 * 2048;

  for (int phase = 0; phase < 2; ++phase) {
    const int c = phase ? pr : (31 - pr);   // 64-row chunk, big first
    const int qw = c * 64;
    const int ntiles = c + 1;

    bf16x8 qf[4][2];
#pragma unroll
    for (int bi = 0; bi < 4; ++bi)
#pragma unroll
      for (int ks = 0; ks < 2; ++ks)
        qf[bi][ks] = ldfrag(Q + (size_t)(b * 2048 + qw + bi * 16 + ln) * 1024 + h * 64 + ks * 32 + quad * 8);

    floatx4 ot[4][4];
#pragma unroll
    for (int ai = 0; ai < 4; ++ai)
#pragma unroll
      for (int bi = 0; bi < 4; ++bi) ot[ai][bi] = floatx4{0.f, 0.f, 0.f, 0.f};
    float li[4] = {0.f, 0.f, 0.f, 0.f};

    for (int t = wave; t < ntiles; t += 4) {
      const int kv0 = t * 64;
      const bool diag = (t == ntiles - 1);

      const ushort_t* kp = kbase + (size_t)(kv0 + ln) * 1024 + quad * 8;
      bf16x8 kf[4][2];
#pragma unroll
      for (int mi = 0; mi < 4; ++mi)
#pragma unroll
        for (int ks = 0; ks < 2; ++ks)
          kf[mi][ks] = ldfrag(kp + mi * 16 * 1024 + ks * 32);

      const ushort_t* vp = vbase + (size_t)ln * 2048 + kv0 + quad * 8;
      bf16x8 vf[4][2];
#pragma unroll
      for (int ai = 0; ai < 4; ++ai)
#pragma unroll
        for (int ks = 0; ks < 2; ++ks)
          vf[ai][ks] = ldfrag(vp + ai * 16 * 2048 + ks * 32);

#pragma unroll
      for (int bi = 0; bi < 4; ++bi) {
        floatx4 st[4];
#pragma unroll
        for (int mi = 0; mi < 4; ++mi) st[mi] = floatx4{0.f, 0.f, 0.f, 0.f};
#pragma unroll
        for (int mi = 0; mi < 4; ++mi) {
          st[mi] = __builtin_amdgcn_mfma_f32_16x16x32_bf16(kf[mi][0], qf[bi][0], st[mi], 0, 0, 0);
          st[mi] = __builtin_amdgcn_mfma_f32_16x16x32_bf16(kf[mi][1], qf[bi][1], st[mi], 0, 0, 0);
        }

        const int qrow = qw + bi * 16 + ln;
        float p[4][4];
        if (diag) {
#pragma unroll
          for (int mi = 0; mi < 4; ++mi)
#pragma unroll
            for (int r = 0; r < 4; ++r) {
              const int kv = kv0 + mi * 16 + quad * 4 + r;
              const float e = __builtin_amdgcn_exp2f(st[mi][r]);
              p[mi][r] = (kv > qrow) ? 0.f : e;
            }
        } else {
#pragma unroll
          for (int mi = 0; mi < 4; ++mi)
#pragma unroll
            for (int r = 0; r < 4; ++r) p[mi][r] = __builtin_amdgcn_exp2f(st[mi][r]);
        }

        unsigned d[4][2];
#pragma unroll
        for (int mi = 0; mi < 4; ++mi) {
          li[bi] += (p[mi][0] + p[mi][1]) + (p[mi][2] + p[mi][3]);
          d[mi][0] = __builtin_amdgcn_perm(
              __builtin_bit_cast(unsigned, p[mi][1]), __builtin_bit_cast(unsigned, p[mi][0]), 0x07060302u);
          d[mi][1] = __builtin_amdgcn_perm(
              __builtin_bit_cast(unsigned, p[mi][3]), __builtin_bit_cast(unsigned, p[mi][2]), 0x07060302u);
        }

        bf16x8 pb[2];
#pragma unroll
        for (int ks = 0; ks < 2; ++ks) {
          uintx4 w;
#pragma unroll
          for (int jj = 0; jj < 4; ++jj) {
            const int idx = (jj >> 1) ? idxB : idxA;
            const int lo = __builtin_amdgcn_ds_bpermute(idx, (int)d[2 * ks][jj & 1]);
            const int hi = __builtin_amdgcn_ds_bpermute(idx, (int)d[2 * ks + 1][jj & 1]);
            w[jj] = (unsigned)(hiq ? hi : lo);
          }
          pb[ks] = __builtin_bit_cast(bf16x8, w);
        }

#pragma unroll
        for (int ai = 0; ai < 4; ++ai) {
          ot[ai][bi] = __builtin_amdgcn_mfma_f32_16x16x32_bf16(vf[ai][0], pb[0], ot[ai][bi], 0, 0, 0);
          ot[ai][bi] = __builtin_amdgcn_mfma_f32_16x16x32_bf16(vf[ai][1], pb[1], ot[ai][bi], 0, 0, 0);
        }
      }
    }

    // --- 4-way additive combine, 2-round tree ---
    __syncthreads();  // tiles done; Cb buffers safe to (re)write
    if (wave == 1) {
#pragma unroll
      for (int bi = 0; bi < 4; ++bi) {
#pragma unroll
        for (int ai = 0; ai < 4; ++ai)
          *(floatx4*)&CbA[bi * 16 + ln][ai * 16 + quad * 4] = ot[ai][bi];
        lbA[lane][bi] = li[bi];
      }
    } else if (wave == 3) {
#pragma unroll
      for (int bi = 0; bi < 4; ++bi) {
#pragma unroll
        for (int ai = 0; ai < 4; ++ai)
          *(floatx4*)&CbB[bi * 16 + ln][ai * 16 + quad * 4] = ot[ai][bi];
        lbB[lane][bi] = li[bi];
      }
    }
    __syncthreads();
    if (wave == 0) {
#pragma unroll
      for (int bi = 0; bi < 4; ++bi) {
#pragma unroll
        for (int ai = 0; ai < 4; ++ai) {
          const floatx4 o = *(const floatx4*)&CbA[bi * 16 + ln][ai * 16 + quad * 4];
#pragma unroll
          for (int r = 0; r < 4; ++r) ot[ai][bi][r] += o[r];
        }
        li[bi] += lbA[lane][bi];
      }
    } else if (wave == 2) {
#pragma unroll
      for (int bi = 0; bi < 4; ++bi) {
#pragma unroll
        for (int ai = 0; ai < 4; ++ai) {
          const floatx4 o = *(const floatx4*)&CbB[bi * 16 + ln][ai * 16 + quad * 4];
#pragma unroll
          for (int r = 0; r < 4; ++r) ot[ai][bi][r] += o[r];
        }
        li[bi] += lbB[lane][bi];
      }
    }
    __syncthreads();
    if (wave == 2) {
#pragma unroll
      for (int bi = 0; bi < 4; ++bi) {
#pragma unroll
        for (int ai = 0; ai < 4; ++ai)
          *(floatx4*)&CbA[bi * 16 + ln][ai * 16 + quad * 4] = ot[ai][bi];
        lbA[lane][bi] = li[bi];
      }
    }
    __syncthreads();
    if (wave == 0) {
#pragma unroll
      for (int bi = 0; bi < 4; ++bi) {
#pragma unroll
        for (int ai = 0; ai < 4; ++ai) {
          const floatx4 o = *(const floatx4*)&CbA[bi * 16 + ln][ai * 16 + quad * 4];
#pragma unroll
          for (int r = 0; r < 4; ++r) ot[ai][bi][r] += o[r];
        }
        li[bi] += lbA[lane][bi];
      }

      // epilogue: normalize + store 64 rows
#pragma unroll
      for (int bi = 0; bi < 4; ++bi) {
        li[bi] += __shfl_xor(li[bi], 16);
        li[bi] += __shfl_xor(li[bi], 32);
        const float inv = 1.0f / li[bi];
        const int qrow = qw + bi * 16 + ln;
        if (f32o) {
          float* of = (float*)out;
#pragma unroll
          for (int ai = 0; ai < 4; ++ai) {
            floatx4 o;
#pragma unroll
            for (int r = 0; r < 4; ++r) o[r] = ot[ai][bi][r] * inv;
            *(floatx4*)(of + (size_t)(b * 2048 + qrow) * 1024 + h * 64 + ai * 16 + quad * 4) = o;
          }
        } else {
          ushort_t* ob = (ushort_t*)out;
#pragma unroll
          for (int ai = 0; ai < 4; ++ai) {
            ushortx4 pk;
#pragma unroll
            for (int r = 0; r < 4; ++r) pk[r] = f2bf(ot[ai][bi][r] * inv);
            *(ushortx4*)(ob + (size_t)(b * 2048 + qrow) * 1024 + h * 64 + ai * 16 + quad * 4) = pk;
          }
        }
      }
    }
  }
}

// ---------------------------------------------------------------------------
extern "C" void kernel_launch(void* const* d_in, const int* in_sizes, int n_in,
                              void* d_out, int out_size, void* d_ws, size_t ws_size,
                              hipStream_t stream) {
  char* w = (char*)d_ws;
  int* flag = (int*)w;
  size_t off = 256;
  ushort_t* xb  = (ushort_t*)(w + off); off += (size_t)4194304 * 2;
  ushort_t* wqb = (ushort_t*)(w + off); off += (size_t)1048576 * 2;
  ushort_t* wkb = (ushort_t*)(w + off); off += (size_t)1048576 * 2;
  ushort_t* wvb = (ushort_t*)(w + off); off += (size_t)1048576 * 2;
  float* biasf  = (float*)(w + off);    off += (size_t)3 * 1024 * 4;
  ushort_t* Qw  = (ushort_t*)(w + off); off += (size_t)4194304 * 2;
  ushort_t* Kw  = (ushort_t*)(w + off); off += (size_t)4194304 * 2;
  ushort_t* Vtw = (ushort_t*)(w + off);

  convert_all<<<dim3(2048, 5), 256, 0, stream>>>(
      d_in[0], d_in[1], d_in[3], d_in[5], d_in[2], d_in[4], d_in[6],
      xb, wqb, wkb, wvb, biasf, flag);
  qkv_gemm<<<dim3(8, 32, 3), 256, 0, stream>>>(xb, wqb, wkb, wvb, biasf, Qw, Kw, Vtw);
  flash10<<<512, 256, 0, stream>>>(Qw, Kw, Vtw, d_out, flag);
}